// Round 5
// baseline (759.808 us; speedup 1.0000x reference)
//
#include <hip/hip_runtime.h>
#include <hip/hip_bf16.h>

// Problem: B=256, P=196, E=2048, D=512, A=512
//   att1 = enc[B,P,E] @ W_enc[E,A]  (+b_enc)  -- 105 GFLOP GEMM, M=50176, K=2048, N=512
//   att2 = dh @ W_dec + b_dec                 -- tiny, fused bias adds
//   att  = relu(att1+att2) @ W_full           -- fused into GEMM epilogue
//   alpha= softmax(att, axis=P)               -- b_full dropped (shift-invariant)
//   awe  = einsum(bpe,bp->be)                 -- second streaming pass over enc
//
// ws:  [0,2MB) B_perm bf16 fragment-linear  (ONLY ws use — robust to small ws_size)
// out: awe fp32 [256][2048] then alpha fp32 [256][196]
//      awe region doubles as scratch before K5: att2p fp32 [256][512] at +0,
//      att fp32 [50176] at +131072 floats (ends 181248 < 524288). K2->K3->K4
//      consume them; K5 (reads only alpha+enc) overwrites the region last.
//
// Round-5 note: K5 iterates batches in REVERSE (b = 255 - blockIdx.y) so the
// second pass over enc consumes the tail of enc that K3 left resident in the
// 256MB L3 (ascending sweep leaves the tail cached; ascending re-read would
// be the LRU worst case). Pure block permutation — cannot regress.

typedef __attribute__((ext_vector_type(8))) short bf16x8;
typedef __attribute__((ext_vector_type(4))) float f32x4;

constexpr int Kdim = 2048;
constexpr int Ndim = 512;
constexpr int BM   = 64;            // block tile M (784 blocks, 50176/64 exact)
constexpr int BK   = 32;
constexpr int KT   = Kdim / BK;     // 64
constexpr int LDA_PAD = 40;         // ushort stride: 80 B -> 16B-aligned b128, <=2-way alias (free)

__device__ __forceinline__ unsigned short bfbits(float x) {
    __hip_bfloat16 h = __float2bfloat16(x);
    unsigned short u;
    __builtin_memcpy(&u, &h, 2);
    return u;
}

// ---------------------------------------------------------------------------
// K1: W_enc fp32 [2048][512] -> B_perm bf16, fragment-linear:
//     B_perm[((ks*32+nf)*64+lane)*8+j] = bf16(W_enc[ks*32+(lane>>4)*8+j][nf*16+(lane&15)])
__global__ __launch_bounds__(256) void cast_permute_kernel(
    const float* __restrict__ W, unsigned short* __restrict__ Bp)
{
    int t    = blockIdx.x * 256 + threadIdx.x;   // 0..131071
    int lane = t & 63;
    int frag = t >> 6;                           // ks*32+nf
    int ks = frag >> 5, nf = frag & 31;
    int k0  = ks * 32 + (lane >> 4) * 8;
    int col = nf * 16 + (lane & 15);
    unsigned short o[8];
#pragma unroll
    for (int j = 0; j < 8; ++j)
        o[j] = bfbits(W[(size_t)(k0 + j) * Ndim + col]);
    uint4 v;
    v.x = (unsigned)o[0] | ((unsigned)o[1] << 16);
    v.y = (unsigned)o[2] | ((unsigned)o[3] << 16);
    v.z = (unsigned)o[4] | ((unsigned)o[5] << 16);
    v.w = (unsigned)o[6] | ((unsigned)o[7] << 16);
    *reinterpret_cast<uint4*>(Bp + (size_t)t * 8) = v;
}

// ---------------------------------------------------------------------------
// K2: att2p[b][a] = dh[b] . W_dec[:,a] + b_dec[a] + b_enc[a]
__global__ __launch_bounds__(256) void att2_kernel(
    const float* __restrict__ dh, const float* __restrict__ Wd,
    const float* __restrict__ bdec, const float* __restrict__ benc,
    float* __restrict__ att2p)
{
    __shared__ float sh[4][512];
    int b0 = blockIdx.x * 4;
    int t  = threadIdx.x;
    for (int i = t; i < 4 * 512; i += 256)
        sh[i >> 9][i & 511] = dh[(size_t)b0 * 512 + i];
    __syncthreads();
    int a = t;
    float acc0[4] = {0,0,0,0}, acc1[4] = {0,0,0,0};
    for (int d = 0; d < 512; ++d) {
        float w0 = Wd[(size_t)d * 512 + a];
        float w1 = Wd[(size_t)d * 512 + a + 256];
#pragma unroll
        for (int i = 0; i < 4; ++i) {
            acc0[i] += sh[i][d] * w0;
            acc1[i] += sh[i][d] * w1;
        }
    }
    float c0 = bdec[a] + benc[a];
    float c1 = bdec[a + 256] + benc[a + 256];
#pragma unroll
    for (int i = 0; i < 4; ++i) {
        att2p[(size_t)(b0 + i) * 512 + a]       = acc0[i] + c0;
        att2p[(size_t)(b0 + i) * 512 + a + 256] = acc1[i] + c1;
    }
}

// ---------------------------------------------------------------------------
// K3: fused GEMM. 784 blocks x 512 threads (8 waves, 1M x 8N).
//     Block tile 64(M) x 512(N full). A via LDS (fp32->bf16 reg-staged,
//     double-buffered); B fragments straight from L2 (fragment-linear B_perm).
//     Epilogue: relu(acc + att2p) . W_full reduced over A -> att[row].
__global__ __launch_bounds__(512, 4) void att_gemm_kernel(
    const float* __restrict__ enc, const bf16x8* __restrict__ Bp,
    const float* __restrict__ att2p, const float* __restrict__ Wfull,
    float* __restrict__ att)
{
    __shared__ unsigned short Alds[2][BM][LDA_PAD];
    __shared__ float a2sh[2][512];
    __shared__ float attp[8][BM];

    const int tid  = threadIdx.x;
    const int lane = tid & 63;
    const int wid  = tid >> 6;          // wave = 64-col chunk of N
    const int bm   = blockIdx.x * BM;

    // A staging: thread -> row sr (0..63), 4 floats at K-col sc
    const int sr = tid >> 3;
    const int sc = (tid & 7) * 4;
    const float* gA = enc + (size_t)(bm + sr) * Kdim + sc;

    // B fragments (bf16x8 units): frag (kt,i) at gB[kt*2048 + i*64]
    const bf16x8* gB = Bp + (size_t)(wid * 4) * 64 + lane;

    f32x4 acc[4][4] = {};   // [mf][nfi]

    // ---- prologue: stage kt=0 ----
    {
        float4 a0 = *(const float4*)(gA);
        union { unsigned long long u; unsigned short s[4]; } w;
        w.s[0] = bfbits(a0.x); w.s[1] = bfbits(a0.y);
        w.s[2] = bfbits(a0.z); w.s[3] = bfbits(a0.w);
        *(unsigned long long*)&Alds[0][sr][sc] = w.u;
    }
    __syncthreads();

    for (int kt = 0; kt < KT; ++kt) {
        const int cur = kt & 1;
        const bool more = (kt + 1 < KT);
        // B loads for this kt first (oldest in vmcnt queue -> MFMA waits
        // leave the A prefetch in flight)
        bf16x8 bfr[4];
#pragma unroll
        for (int i = 0; i < 4; ++i) bfr[i] = gB[(size_t)kt * 2048 + i * 64];
        // A prefetch for kt+1 (issue early, consume after MFMAs)
        float4 na;
        if (more) na = *(const float4*)(gA + (kt + 1) * BK);
        // A fragments from LDS
        bf16x8 af[4];
#pragma unroll
        for (int mf = 0; mf < 4; ++mf)
            af[mf] = *(const bf16x8*)&Alds[cur][mf * 16 + (lane & 15)][(lane >> 4) * 8];
#pragma unroll
        for (int mf = 0; mf < 4; ++mf)
#pragma unroll
            for (int i = 0; i < 4; ++i)
                acc[mf][i] = __builtin_amdgcn_mfma_f32_16x16x32_bf16(
                    af[mf], bfr[i], acc[mf][i], 0, 0, 0);
        if (more) {
            union { unsigned long long u; unsigned short s[4]; } w;
            w.s[0] = bfbits(na.x); w.s[1] = bfbits(na.y);
            w.s[2] = bfbits(na.z); w.s[3] = bfbits(na.w);
            *(unsigned long long*)&Alds[cur ^ 1][sr][sc] = w.u;
        }
        __syncthreads();
    }

    // ---- stage att2p rows for the (<=2) batches this block spans ----
    const int b0  = bm / 196;
    const int b1  = (b0 + 1 < 256) ? b0 + 1 : 255;
    a2sh[0][tid] = att2p[(size_t)b0 * 512 + tid];
    a2sh[1][tid] = att2p[(size_t)b1 * 512 + tid];
    __syncthreads();

    // ---- epilogue: relu(acc + att2) . W_full, reduce over cols ----
    const int colbase = wid * 64 + (lane & 15);
    const int thr = (b0 + 1) * 196 - bm;   // local row >= thr -> batch b1
    float wf[4];
#pragma unroll
    for (int i = 0; i < 4; ++i) wf[i] = Wfull[colbase + i * 16];

#pragma unroll
    for (int mf = 0; mf < 4; ++mf) {
        const int rowloc = mf * 16 + (lane >> 4) * 4;
#pragma unroll
        for (int r = 0; r < 4; ++r) {
            const int lr = rowloc + r;
            const float* a2 = a2sh[lr >= thr ? 1 : 0];
            float s = 0.f;
#pragma unroll
            for (int i = 0; i < 4; ++i) {
                float v = acc[mf][i][r] + a2[colbase + i * 16];
                s += fmaxf(v, 0.f) * wf[i];
            }
            s += __shfl_xor(s, 1);
            s += __shfl_xor(s, 2);
            s += __shfl_xor(s, 4);
            s += __shfl_xor(s, 8);
            if ((lane & 15) == 0) attp[wid][lr] = s;
        }
    }
    __syncthreads();
    if (tid < BM) {
        float s = 0.f;
#pragma unroll
        for (int w = 0; w < 8; ++w) s += attp[w][tid];
        att[bm + tid] = s;
    }
}

// ---------------------------------------------------------------------------
// K4: softmax over P=196 per batch
__global__ __launch_bounds__(256) void softmax_kernel(
    const float* __restrict__ att, float* __restrict__ alpha)
{
    __shared__ float red[8];
    int b = blockIdx.x, t = threadIdx.x;
    float v = (t < 196) ? att[b * 196 + t] : -INFINITY;
    float m = v;
#pragma unroll
    for (int mask = 1; mask < 64; mask <<= 1) m = fmaxf(m, __shfl_xor(m, mask));
    if ((t & 63) == 0) red[t >> 6] = m;
    __syncthreads();
    float M = fmaxf(fmaxf(red[0], red[1]), fmaxf(red[2], red[3]));
    float e = (t < 196) ? __expf(v - M) : 0.f;
    float s = e;
#pragma unroll
    for (int mask = 1; mask < 64; mask <<= 1) s += __shfl_xor(s, mask);
    if ((t & 63) == 0) red[4 + (t >> 6)] = s;
    __syncthreads();
    float S = red[4] + red[5] + red[6] + red[7];
    if (t < 196) alpha[b * 196 + t] = e / S;
}

// ---------------------------------------------------------------------------
// K5: awe[b][e] = sum_p alpha[b][p] * enc[b][p][e]
//     grid (8,256), 1 wave/block, thread = one float4 column strip.
//     Batches consumed in REVERSE order for L3 tail reuse after K3's sweep.
__global__ __launch_bounds__(64) void awe_kernel(
    const float* __restrict__ enc, const float* __restrict__ alpha,
    float* __restrict__ awe)
{
    __shared__ float al[196];
    const int b  = 255 - (int)blockIdx.y;   // reverse: hit K3's L3-resident tail first
    const int t  = threadIdx.x;
    const int e0 = blockIdx.x * 256 + t * 4;
    for (int i = t; i < 196; i += 64) al[i] = alpha[b * 196 + i];
    __syncthreads();
    const float4* p = (const float4*)(enc + (size_t)b * 196 * 2048 + e0);
    float4 acc0 = {0.f,0.f,0.f,0.f}, acc1 = {0.f,0.f,0.f,0.f};
#pragma unroll 4
    for (int pp = 0; pp < 196; pp += 2) {
        float a0 = al[pp];
        float a1 = al[pp + 1];            // P=196 even, no tail
        float4 v0 = p[(size_t)pp * 512];
        float4 v1 = p[(size_t)(pp + 1) * 512];
        acc0.x += a0 * v0.x; acc0.y += a0 * v0.y; acc0.z += a0 * v0.z; acc0.w += a0 * v0.w;
        acc1.x += a1 * v1.x; acc1.y += a1 * v1.y; acc1.z += a1 * v1.z; acc1.w += a1 * v1.w;
    }
    float4 r;
    r.x = acc0.x + acc1.x; r.y = acc0.y + acc1.y;
    r.z = acc0.z + acc1.z; r.w = acc0.w + acc1.w;
    *(float4*)(awe + (size_t)b * 2048 + e0) = r;
}

// ---------------------------------------------------------------------------
extern "C" void kernel_launch(void* const* d_in, const int* in_sizes, int n_in,
                              void* d_out, int out_size, void* d_ws, size_t ws_size,
                              hipStream_t stream) {
    const float* enc   = (const float*)d_in[0];
    const float* dh    = (const float*)d_in[1];
    const float* Wenc  = (const float*)d_in[2];
    const float* benc  = (const float*)d_in[3];
    const float* Wdec  = (const float*)d_in[4];
    const float* bdec  = (const float*)d_in[5];
    const float* Wfull = (const float*)d_in[6];
    // d_in[7] = b_full: dropped (softmax shift-invariant; att not an output)

    float* out   = (float*)d_out;
    float* awe   = out;                     // [256][2048], written LAST (K5)
    float* alpha = out + 256 * 2048;        // [256][196],  written by K4

    // transient scratch inside the awe region (dead before K5 runs):
    float* att2p = out;                     // [256][512]  = 131072 floats
    float* att   = out + 131072;            // [50176]     -> ends at 181248 < 524288

    unsigned short* Bp = (unsigned short*)d_ws;   // 2 MB, only ws use

    cast_permute_kernel<<<512, 256, 0, stream>>>(Wenc, Bp);
    att2_kernel<<<64, 256, 0, stream>>>(dh, Wdec, bdec, benc, att2p);
    att_gemm_kernel<<<784, 512, 0, stream>>>(enc, (const bf16x8*)Bp, att2p, Wfull, att);
    softmax_kernel<<<256, 256, 0, stream>>>(att, alpha);
    awe_kernel<<<dim3(8, 256), 64, 0, stream>>>(enc, alpha, awe);
}